// Round 19
// baseline (111.116 us; speedup 1.0000x reference)
//
#include <hip/hip_runtime.h>
#include <hip/hip_bf16.h>

#define BATCH  4096
#define DIM    1024
#define NCHUNK 16          // 256-col chunks per row in STATS
#define BM     128
#define BN     256
#define BKK    64
#define NKT    (DIM / BKK) // 16 K-tiles
#define INVT   14.285714285714286f
#define C1     20.609929f  // INVT * log2(e); exp(INVT*(d-1)) == exp2(d*C1 - C1)
#define EPSV   1e-8f
#define NEGINF -3.0e38f

typedef __bf16 bf16x8 __attribute__((ext_vector_type(8)));
typedef float  f32x4  __attribute__((ext_vector_type(4)));
typedef __attribute__((address_space(3))) void lds_void;
typedef __attribute__((address_space(1))) void gl_void;

// Branchless sorted-desc top-5 insert (9 min/max ops).
__device__ __forceinline__ void top5_insert(float (&t)[5], float v) {
  float a = fmaxf(t[4], v), b;
  b = t[3]; t[4] = fminf(b, a); a = fmaxf(b, a);
  b = t[2]; t[3] = fminf(b, a); a = fmaxf(b, a);
  b = t[1]; t[2] = fminf(b, a); a = fmaxf(b, a);
  b = t[0]; t[1] = fminf(b, a); t[0] = fmaxf(b, a);
}

__device__ __forceinline__ void ce_desc(float& a, float& b) {
  const float hi = fmaxf(a, b), lo = fminf(a, b);
  a = hi; b = lo;
}

// Merge sorted-desc top5 with lane^msk's: elementwise max vs reversed partner
// list = top-5 multiset; 9-CE network re-sorts.
__device__ __forceinline__ void top5_merge_x(float (&t)[5], int msk) {
  const float b0 = __shfl_xor(t[0], msk);
  const float b1 = __shfl_xor(t[1], msk);
  const float b2 = __shfl_xor(t[2], msk);
  const float b3 = __shfl_xor(t[3], msk);
  const float b4 = __shfl_xor(t[4], msk);
  t[0] = fmaxf(t[0], b4); t[1] = fmaxf(t[1], b3); t[2] = fmaxf(t[2], b2);
  t[3] = fmaxf(t[3], b1); t[4] = fmaxf(t[4], b0);
  ce_desc(t[0], t[1]); ce_desc(t[3], t[4]); ce_desc(t[2], t[4]);
  ce_desc(t[2], t[3]); ce_desc(t[1], t[4]); ce_desc(t[0], t[3]);
  ce_desc(t[0], t[2]); ce_desc(t[1], t[3]); ce_desc(t[1], t[2]);
}

// ---------------- kernel 0: label histogram ----------------
__global__ __launch_bounds__(1024) void k_hist(const long long* __restrict__ LAB,
                                               int* __restrict__ HIST) {
  __shared__ int h[512];
  const int t = threadIdx.x;
  if (t < 512) h[t] = 0;
  __syncthreads();
  for (int i = t; i < BATCH; i += 1024) atomicAdd(&h[(int)LAB[i]], 1);
  __syncthreads();
  if (t < 512) HIST[t] = h[t];
}

// ---------------- kernel 1: row L2-normalize fp32 -> bf16 (+ bf16 self-dot) ----------------
// Wave-per-row: 4 rows/block, pure shfl reduction (no LDS, no __syncthreads).
__global__ __launch_bounds__(256) void k_normalize(const float* __restrict__ X,
                                                   unsigned short* __restrict__ F,
                                                   float* __restrict__ DDIAG) {
  const int row = blockIdx.x * 4 + (threadIdx.x >> 6);
  const int l   = threadIdx.x & 63;
  const float4* xp = (const float4*)(X + (size_t)row * DIM);
  float4 v[4];
  float ss = 0.f;
#pragma unroll
  for (int i = 0; i < 4; ++i) {
    v[i] = xp[l + 64 * i];
    ss += v[i].x*v[i].x + v[i].y*v[i].y + v[i].z*v[i].z + v[i].w*v[i].w;
  }
#pragma unroll
  for (int m = 32; m >= 1; m >>= 1) ss += __shfl_xor(ss, m);
  const float inv = 1.0f / fmaxf(sqrtf(ss), 1e-12f);
  ushort4* fp = (ushort4*)(F + (size_t)row * DIM);
  float s2 = 0.f;
#pragma unroll
  for (int i = 0; i < 4; ++i) {
    const __bf16 b0 = (__bf16)(v[i].x * inv), b1 = (__bf16)(v[i].y * inv);
    const __bf16 b2 = (__bf16)(v[i].z * inv), b3 = (__bf16)(v[i].w * inv);
    const float f0 = (float)b0, f1 = (float)b1, f2 = (float)b2, f3 = (float)b3;
    s2 += f0*f0 + f1*f1 + f2*f2 + f3*f3;   // self-dot of bf16-rounded row
    ushort4 o;
    o.x = __builtin_bit_cast(unsigned short, b0);
    o.y = __builtin_bit_cast(unsigned short, b1);
    o.z = __builtin_bit_cast(unsigned short, b2);
    o.w = __builtin_bit_cast(unsigned short, b3);
    fp[l + 64 * i] = o;
  }
#pragma unroll
  for (int m = 32; m >= 1; m >>= 1) s2 += __shfl_xor(s2, m);
  if (l == 0) DDIAG[row] = s2;
}

// ---------------- kernel 2: fused sim GEMM + per-row stats (128x256, pipe-split) ----------------
// grid = (16 ch, 32 rb), 256 thr = 4 waves (2M x 2N), wave tile 64x128 =
// acc[4][8]. Operand pipe-split: A staged in LDS (shared by the wn-pair),
// B-fragments loaded DIRECTLY global->VGPR (16B per lane; a wave's 64 lanes
// cover 16 cols x one full 64B line = perfectly coalesced, L1/L2-resident).
// LDS reads drop 24->8 per kt/wave (per-CU LDS wall ~30 -> ~10 us); the
// barrier drain now guards only A's 4 global_load_lds. 2 blocks/CU.
__global__ __launch_bounds__(256, 2) void k_fused(const unsigned short* __restrict__ F,
                                                  const long long* __restrict__ LAB,
                                                  float* __restrict__ STATS) {
  __shared__ __align__(16) unsigned short lA[BM * BKK];  // 16 KB (A only)

  const int ch  = blockIdx.x;
  const int rb  = blockIdx.y;
  const int tid = threadIdx.x;
  const int wid = tid >> 6;
  const int l   = tid & 63;
  const int l15 = l & 15;
  const int l4  = l >> 4;
  const int wm  = wid >> 1;        // 0..1
  const int wn  = wid & 1;         // 0..1
  const int swz = (l15 & 7) << 4;  // XOR swizzle (A frag reads only)
  const int rowbase = rb * BM;
  const int colbase = ch * BN;

  f32x4 acc[4][8];
#pragma unroll
  for (int mf = 0; mf < 4; ++mf)
#pragma unroll
    for (int nf = 0; nf < 8; ++nf) acc[mf][nf] = (f32x4){0.f, 0.f, 0.f, 0.f};

  // A staging addresses: linear LDS dest, pre-swizzled global source
  // (16B chunk c fetched from chunk c^(r&7); involution within 128B row).
  const unsigned short* gArow[4];
  int ldsoA[4];
#pragma unroll
  for (int it = 0; it < 4; ++it) {
    const int s = it * 256 + tid;
    const int r = s >> 3;
    const int c = (s & 7) ^ (r & 7);
    ldsoA[it] = s * 16;
    gArow[it] = F + (size_t)(rowbase + r) * DIM + c * 8;
  }
  // Per-lane B byte offset: col = colbase + wn*128 + l15, k-slice l4*16 bytes.
  const unsigned bvo = (unsigned)(colbase + wn * 128 + l15) * (DIM * 2) + l4 * 16;
  const char* Fb = (const char*)F;

  // ---- K loop: 2-barrier, single-buffered A; B direct-from-global ----
#pragma unroll 1
  for (int kt = 0; kt < NKT; ++kt) {
    __syncthreads();                         // prev compute's lA reads done
#pragma unroll
    for (int it = 0; it < 4; ++it)
      __builtin_amdgcn_global_load_lds((gl_void*)(gArow[it] + kt * BKK),
                                       (lds_void*)((char*)lA + ldsoA[it]), 16, 0, 0);
    __syncthreads();                         // vmcnt(0) drain + barrier

#pragma unroll
    for (int kk = 0; kk < 2; ++kk) {
      bf16x8 av[4], bv[8];
      // B: direct global->reg (no swizzle; bit-identical data to LDS path)
#pragma unroll
      for (int nf = 0; nf < 8; ++nf)
        bv[nf] = *(const bf16x8*)(Fb + bvo + nf * (16 * DIM * 2) + kt * (BKK * 2) + kk * 64);
      const int cx = (kk * 64 + l4 * 16) ^ swz;
#pragma unroll
      for (int mf = 0; mf < 4; ++mf)
        av[mf] = *(const bf16x8*)((const char*)lA + (wm * 64 + mf * 16 + l15) * 128 + cx);
#pragma unroll
      for (int mf = 0; mf < 4; ++mf)
#pragma unroll
        for (int nf = 0; nf < 8; ++nf)
          acc[mf][nf] = __builtin_amdgcn_mfma_f32_16x16x32_bf16(av[mf], bv[nf], acc[mf][nf], 0, 0, 0);
    }
  }

  __syncthreads();   // all lA reads done before part-overlay writes

  // ---- epilogue: per-row stats, mf FULLY UNROLLED (static acc indexing) ----
  float* part = (float*)lA;          // overlay: [128 rows][2 wn][8 floats] = 8 KB
  const bool hasdiag = ((rb >> 1) == ch);   // 128-row band intersects 256-col band

  int cl[8];
#pragma unroll
  for (int nf = 0; nf < 8; ++nf)
    cl[nf] = (int)LAB[colbase + wn * 128 + nf * 16 + l15];

#pragma unroll
  for (int mf = 0; mf < 4; ++mf) {
    const int lr0 = wm * 64 + mf * 16 + l4 * 4;   // local row of j=0
    int rlv[4];
#pragma unroll
    for (int j = 0; j < 4; ++j) rlv[j] = (int)LAB[rowbase + lr0 + j];

    float pe4[4], sa4[4], t54[4][5];
#pragma unroll
    for (int j = 0; j < 4; ++j) {
      pe4[j] = 0.f; sa4[j] = 0.f;
#pragma unroll
      for (int k = 0; k < 5; ++k) t54[j][k] = NEGINF;
    }

#define EPI_BODY(POSEXPR)                                      \
    _Pragma("unroll")                                          \
    for (int nf = 0; nf < 8; ++nf) {                           \
      _Pragma("unroll")                                        \
      for (int j = 0; j < 4; ++j) {                            \
        const float d = acc[mf][nf][j];                        \
        const float e = exp2f(fmaf(d, C1, -C1));               \
        const bool same = (rlv[j] == cl[nf]);                  \
        pe4[j] += (POSEXPR) ? e : 0.f;                         \
        sa4[j] += e;                                           \
        top5_insert(t54[j], same ? 0.f : d);                   \
      }                                                        \
    }

    if (hasdiag) {
      EPI_BODY(same && ((rowbase + lr0 + j) != (colbase + wn * 128 + nf * 16 + l15)))
    } else {
      EPI_BODY(same)
    }
#undef EPI_BODY

    // merge the 16 lanes (l15) holding each row
#pragma unroll
    for (int j = 0; j < 4; ++j) {
#pragma unroll
      for (int msk = 1; msk < 16; msk <<= 1) {
        pe4[j] += __shfl_xor(pe4[j], msk);
        sa4[j] += __shfl_xor(sa4[j], msk);
        top5_merge_x(t54[j], msk);
      }
    }

    if (l15 == 0) {
#pragma unroll
      for (int j = 0; j < 4; ++j) {
        float4* dp = (float4*)(part + ((size_t)(lr0 + j) * 2 + wn) * 8);
        dp[0] = make_float4(pe4[j], sa4[j], t54[j][0], t54[j][1]);
        dp[1] = make_float4(t54[j][2], t54[j][3], t54[j][4], 0.f);
      }
    }
  }

  __syncthreads();

  // ---- combine the 2 wn-partials per row, write STATS [row][chunk][8] ----
  if (tid < BM) {
    const float* p0 = part + (size_t)tid * 2 * 8;
    float pe = 0.f, sa = 0.f;
    float t5[5] = {NEGINF, NEGINF, NEGINF, NEGINF, NEGINF};
#pragma unroll
    for (int q = 0; q < 2; ++q) {
      const float4 a = *(const float4*)(p0 + q * 8);
      const float4 b = *(const float4*)(p0 + q * 8 + 4);
      pe += a.x; sa += a.y;
      top5_insert(t5, a.z); top5_insert(t5, a.w);
      top5_insert(t5, b.x); top5_insert(t5, b.y); top5_insert(t5, b.z);
    }
    float4* dst = (float4*)(STATS + ((size_t)(rowbase + tid) * NCHUNK + ch) * 8);
    dst[0] = make_float4(pe, sa, t5[0], t5[1]);
    dst[1] = make_float4(t5[2], t5[3], t5[4], 0.f);
  }
}

// ---------------- kernel 3: per-row finalize -> per-block partial ----------------
__global__ __launch_bounds__(256) void k_rowloss(const float* __restrict__ STATS,
                                                 const long long* __restrict__ LAB,
                                                 const float* __restrict__ DDIAG,
                                                 const int* __restrict__ HIST,
                                                 float* __restrict__ PART) {
  const int row = blockIdx.x * 256 + threadIdx.x;
  const float* sp = STATS + (size_t)row * NCHUNK * 8;
  float pe = 0.f, sa = 0.f;
  float t5[5] = {NEGINF, NEGINF, NEGINF, NEGINF, NEGINF};
  for (int c = 0; c < NCHUNK; ++c) {
    const float4 q0 = *(const float4*)(sp + c * 8);
    const float4 q1 = *(const float4*)(sp + c * 8 + 4);
    pe += q0.x; sa += q0.y;
    top5_insert(t5, q0.z); top5_insert(t5, q0.w);
    top5_insert(t5, q1.x); top5_insert(t5, q1.y); top5_insert(t5, q1.z);
  }
  const float ediag = exp2f(fmaf(DDIAG[row], C1, -C1));  // exp(s_ii - M)
  const float ne = sa - pe - ediag;                      // sum over true negatives
  const int cn = BATCH - HIST[(int)LAB[row]];            // num_neg
  const float EM = exp2f(-C1);                           // exp(0 - M)
  const float sneg = ne + (float)(BATCH - cn) * EM;      // exp_neg_sum (zeros incl.)
  const int kf = cn < 5 ? cn : 5;
  float eh[5], Sh = 0.f;
#pragma unroll
  for (int k = 0; k < 5; ++k) {
    const float dk = (k < kf) ? t5[k] : 0.f;             // top-5 as dot values
    eh[k] = exp2f(fmaf(dk, C1, -C1));                    // exp(dk*INVT - M)
    Sh += eh[k];
  }
  float lsum = 0.f;
#pragma unroll
  for (int k = 0; k < 5; ++k) {
    const float denom = pe + Sh + sneg - eh[k];
    lsum += __logf(pe / (denom + EPSV) + EPSV);
  }
#pragma unroll
  for (int m = 32; m >= 1; m >>= 1) lsum += __shfl_xor(lsum, m);
  __shared__ float wsum[4];
  if ((threadIdx.x & 63) == 0) wsum[threadIdx.x >> 6] = lsum;
  __syncthreads();
  if (threadIdx.x == 0) PART[blockIdx.x] = wsum[0] + wsum[1] + wsum[2] + wsum[3];
}

// ---------------- kernel 4: final deterministic reduce ----------------
__global__ void k_final(const float* __restrict__ PART, float* __restrict__ OUT) {
  if (threadIdx.x == 0) {
    float s = 0.f;
    for (int i = 0; i < 16; ++i) s += PART[i];
    OUT[0] = -s / (float)(BATCH * 5);
  }
}

extern "C" void kernel_launch(void* const* d_in, const int* in_sizes, int n_in,
                              void* d_out, int out_size, void* d_ws, size_t ws_size,
                              hipStream_t stream) {
  const float* X = (const float*)d_in[0];
  const long long* LAB = (const long long*)d_in[1];
  float* OUT = (float*)d_out;

  unsigned short* F = (unsigned short*)d_ws;                                   // 8 MB bf16
  float* STATS = (float*)((char*)d_ws + (size_t)8 * 1024 * 1024);              // 2 MB
  float* PART  = (float*)((char*)d_ws + (size_t)12 * 1024 * 1024);             // 64 B
  float* DDIAG = (float*)((char*)d_ws + (size_t)12 * 1024 * 1024 + 4096);      // 16 KB
  int*   HIST  = (int*)((char*)d_ws + (size_t)12 * 1024 * 1024 + 4096 + 16384); // 2 KB

  k_hist<<<1, 1024, 0, stream>>>(LAB, HIST);
  k_normalize<<<BATCH / 4, 256, 0, stream>>>(X, F, DDIAG);
  dim3 g2(BATCH / BN, BATCH / BM);
  k_fused<<<g2, 256, 0, stream>>>(F, LAB, STATS);
  k_rowloss<<<BATCH / 256, 256, 0, stream>>>(STATS, LAB, DDIAG, HIST, PART);
  k_final<<<1, 64, 0, stream>>>(PART, OUT);
}

// Round 20
// 73.729 us; speedup vs baseline: 1.5071x; 1.5071x over previous
//
#include <hip/hip_runtime.h>
#include <hip/hip_bf16.h>

#define BATCH  4096
#define DIM    1024
#define NCHUNK 16          // 256-col chunks per row in STATS
#define BM     128
#define BN     256
#define BKK    64
#define NKT    (DIM / BKK) // 16 K-tiles
#define INVT   14.285714285714286f
#define C1     20.609929f  // INVT * log2(e); exp(INVT*(d-1)) == exp2(d*C1 - C1)
#define EPSV   1e-8f
#define NEGINF -3.0e38f

typedef __bf16 bf16x8 __attribute__((ext_vector_type(8)));
typedef float  f32x4  __attribute__((ext_vector_type(4)));
typedef __attribute__((address_space(3))) void lds_void;
typedef __attribute__((address_space(1))) void gl_void;

// Branchless sorted-desc top-5 insert (9 min/max ops).
__device__ __forceinline__ void top5_insert(float (&t)[5], float v) {
  float a = fmaxf(t[4], v), b;
  b = t[3]; t[4] = fminf(b, a); a = fmaxf(b, a);
  b = t[2]; t[3] = fminf(b, a); a = fmaxf(b, a);
  b = t[1]; t[2] = fminf(b, a); a = fmaxf(b, a);
  b = t[0]; t[1] = fminf(b, a); t[0] = fmaxf(b, a);
}

__device__ __forceinline__ void ce_desc(float& a, float& b) {
  const float hi = fmaxf(a, b), lo = fminf(a, b);
  a = hi; b = lo;
}

// Merge sorted-desc top5 with lane^msk's: elementwise max vs reversed partner
// list = top-5 multiset; 9-CE network re-sorts.
__device__ __forceinline__ void top5_merge_x(float (&t)[5], int msk) {
  const float b0 = __shfl_xor(t[0], msk);
  const float b1 = __shfl_xor(t[1], msk);
  const float b2 = __shfl_xor(t[2], msk);
  const float b3 = __shfl_xor(t[3], msk);
  const float b4 = __shfl_xor(t[4], msk);
  t[0] = fmaxf(t[0], b4); t[1] = fmaxf(t[1], b3); t[2] = fmaxf(t[2], b2);
  t[3] = fmaxf(t[3], b1); t[4] = fmaxf(t[4], b0);
  ce_desc(t[0], t[1]); ce_desc(t[3], t[4]); ce_desc(t[2], t[4]);
  ce_desc(t[2], t[3]); ce_desc(t[1], t[4]); ce_desc(t[0], t[3]);
  ce_desc(t[0], t[2]); ce_desc(t[1], t[3]); ce_desc(t[1], t[2]);
}

// ---------------- kernel 0: label histogram ----------------
__global__ __launch_bounds__(1024) void k_hist(const long long* __restrict__ LAB,
                                               int* __restrict__ HIST) {
  __shared__ int h[512];
  const int t = threadIdx.x;
  if (t < 512) h[t] = 0;
  __syncthreads();
  for (int i = t; i < BATCH; i += 1024) atomicAdd(&h[(int)LAB[i]], 1);
  __syncthreads();
  if (t < 512) HIST[t] = h[t];
}

// ---------------- kernel 1: row L2-normalize fp32 -> bf16 (+ bf16 self-dot) ----------------
// Wave-per-row: 4 rows/block, pure shfl reduction (no LDS, no __syncthreads).
__global__ __launch_bounds__(256) void k_normalize(const float* __restrict__ X,
                                                   unsigned short* __restrict__ F,
                                                   float* __restrict__ DDIAG) {
  const int row = blockIdx.x * 4 + (threadIdx.x >> 6);
  const int l   = threadIdx.x & 63;
  const float4* xp = (const float4*)(X + (size_t)row * DIM);
  float4 v[4];
  float ss = 0.f;
#pragma unroll
  for (int i = 0; i < 4; ++i) {
    v[i] = xp[l + 64 * i];
    ss += v[i].x*v[i].x + v[i].y*v[i].y + v[i].z*v[i].z + v[i].w*v[i].w;
  }
#pragma unroll
  for (int m = 32; m >= 1; m >>= 1) ss += __shfl_xor(ss, m);
  const float inv = 1.0f / fmaxf(sqrtf(ss), 1e-12f);
  ushort4* fp = (ushort4*)(F + (size_t)row * DIM);
  float s2 = 0.f;
#pragma unroll
  for (int i = 0; i < 4; ++i) {
    const __bf16 b0 = (__bf16)(v[i].x * inv), b1 = (__bf16)(v[i].y * inv);
    const __bf16 b2 = (__bf16)(v[i].z * inv), b3 = (__bf16)(v[i].w * inv);
    const float f0 = (float)b0, f1 = (float)b1, f2 = (float)b2, f3 = (float)b3;
    s2 += f0*f0 + f1*f1 + f2*f2 + f3*f3;   // self-dot of bf16-rounded row
    ushort4 o;
    o.x = __builtin_bit_cast(unsigned short, b0);
    o.y = __builtin_bit_cast(unsigned short, b1);
    o.z = __builtin_bit_cast(unsigned short, b2);
    o.w = __builtin_bit_cast(unsigned short, b3);
    fp[l + 64 * i] = o;
  }
#pragma unroll
  for (int m = 32; m >= 1; m >>= 1) s2 += __shfl_xor(s2, m);
  if (l == 0) DDIAG[row] = s2;
}

// ---------------- kernel 2: fused sim GEMM + per-row stats (128x256) ----------------
// grid = (16 ch, 32 rb), 256 thr = 4 waves (2M x 2N), wave tile 64x128 =
// acc[4][8]. Single-buffered 48 KB LDS, 2-barrier loop, 2 blocks/CU.
// ANTI-LOCKSTEP: co-resident neighbor blocks (adjacent ch, same rb) start
// their K sweep 8 tiles apart ((ch^rb)&1), so their stage-drain phases
// interleave instead of colliding (K order is commutative; A panel stays
// L2-resident either way).
__global__ __launch_bounds__(256, 2) void k_fused(const unsigned short* __restrict__ F,
                                                  const long long* __restrict__ LAB,
                                                  float* __restrict__ STATS) {
  __shared__ __align__(16) unsigned short lA[BM * BKK];  // 16 KB
  __shared__ __align__(16) unsigned short lB[BN * BKK];  // 32 KB

  const int ch  = blockIdx.x;
  const int rb  = blockIdx.y;
  const int tid = threadIdx.x;
  const int wid = tid >> 6;
  const int l   = tid & 63;
  const int l15 = l & 15;
  const int l4  = l >> 4;
  const int wm  = wid >> 1;        // 0..1
  const int wn  = wid & 1;         // 0..1
  const int swz = (l15 & 7) << 4;  // XOR swizzle: row%8 == l15&7 for frag reads
  const int kph = ((ch ^ rb) & 1) << 3;   // K-phase offset: 0 or 8
  const int rowbase = rb * BM;
  const int colbase = ch * BN;

  f32x4 acc[4][8];
#pragma unroll
  for (int mf = 0; mf < 4; ++mf)
#pragma unroll
    for (int nf = 0; nf < 8; ++nf) acc[mf][nf] = (f32x4){0.f, 0.f, 0.f, 0.f};

  // Precomputed staging addresses. Linear LDS dest, global source pre-swizzled
  // (16B chunk c fetched from chunk c^(r&7); involution within the 128B row).
  const unsigned short* gArow[4];
  const unsigned short* gBrow[8];
  int ldsoA[4], ldsoB[8];
#pragma unroll
  for (int it = 0; it < 4; ++it) {
    const int s = it * 256 + tid;
    const int r = s >> 3;
    const int c = (s & 7) ^ (r & 7);
    ldsoA[it] = s * 16;
    gArow[it] = F + (size_t)(rowbase + r) * DIM + c * 8;
  }
#pragma unroll
  for (int it = 0; it < 8; ++it) {
    const int s = it * 256 + tid;
    const int r = s >> 3;
    const int c = (s & 7) ^ (r & 7);
    ldsoB[it] = s * 16;
    gBrow[it] = F + (size_t)(colbase + r) * DIM + c * 8;
  }

  // ---- K loop: 2-barrier, single-buffered, phase-offset K order ----
#pragma unroll 1
  for (int t = 0; t < NKT; ++t) {
    const int kt = (t + kph) & (NKT - 1);
    __syncthreads();                         // prev compute's LDS reads done
#pragma unroll
    for (int it = 0; it < 4; ++it)
      __builtin_amdgcn_global_load_lds((gl_void*)(gArow[it] + kt * BKK),
                                       (lds_void*)((char*)lA + ldsoA[it]), 16, 0, 0);
#pragma unroll
    for (int it = 0; it < 8; ++it)
      __builtin_amdgcn_global_load_lds((gl_void*)(gBrow[it] + kt * BKK),
                                       (lds_void*)((char*)lB + ldsoB[it]), 16, 0, 0);
    __syncthreads();                         // vmcnt(0) drain + barrier

#pragma unroll
    for (int kk = 0; kk < 2; ++kk) {
      bf16x8 av[4], bv[8];
      const int cx = (kk * 64 + l4 * 16) ^ swz;
#pragma unroll
      for (int mf = 0; mf < 4; ++mf)
        av[mf] = *(const bf16x8*)((const char*)lA + (wm * 64 + mf * 16 + l15) * 128 + cx);
#pragma unroll
      for (int nf = 0; nf < 8; ++nf)
        bv[nf] = *(const bf16x8*)((const char*)lB + (wn * 128 + nf * 16 + l15) * 128 + cx);
#pragma unroll
      for (int mf = 0; mf < 4; ++mf)
#pragma unroll
        for (int nf = 0; nf < 8; ++nf)
          acc[mf][nf] = __builtin_amdgcn_mfma_f32_16x16x32_bf16(av[mf], bv[nf], acc[mf][nf], 0, 0, 0);
    }
  }

  __syncthreads();   // all LDS reads done before part-overlay writes

  // ---- epilogue: per-row stats, mf FULLY UNROLLED (static acc indexing) ----
  float* part = (float*)lA;          // overlay: [128 rows][2 wn][8 floats] = 8 KB
  const bool hasdiag = ((rb >> 1) == ch);   // 128-row band intersects 256-col band

  int cl[8];
#pragma unroll
  for (int nf = 0; nf < 8; ++nf)
    cl[nf] = (int)LAB[colbase + wn * 128 + nf * 16 + l15];

#pragma unroll
  for (int mf = 0; mf < 4; ++mf) {
    const int lr0 = wm * 64 + mf * 16 + l4 * 4;   // local row of j=0
    int rlv[4];
#pragma unroll
    for (int j = 0; j < 4; ++j) rlv[j] = (int)LAB[rowbase + lr0 + j];

    float pe4[4], sa4[4], t54[4][5];
#pragma unroll
    for (int j = 0; j < 4; ++j) {
      pe4[j] = 0.f; sa4[j] = 0.f;
#pragma unroll
      for (int k = 0; k < 5; ++k) t54[j][k] = NEGINF;
    }

#define EPI_BODY(POSEXPR)                                      \
    _Pragma("unroll")                                          \
    for (int nf = 0; nf < 8; ++nf) {                           \
      _Pragma("unroll")                                        \
      for (int j = 0; j < 4; ++j) {                            \
        const float d = acc[mf][nf][j];                        \
        const float e = exp2f(fmaf(d, C1, -C1));               \
        const bool same = (rlv[j] == cl[nf]);                  \
        pe4[j] += (POSEXPR) ? e : 0.f;                         \
        sa4[j] += e;                                           \
        top5_insert(t54[j], same ? 0.f : d);                   \
      }                                                        \
    }

    if (hasdiag) {
      EPI_BODY(same && ((rowbase + lr0 + j) != (colbase + wn * 128 + nf * 16 + l15)))
    } else {
      EPI_BODY(same)
    }
#undef EPI_BODY

    // merge the 16 lanes (l15) holding each row
#pragma unroll
    for (int j = 0; j < 4; ++j) {
#pragma unroll
      for (int msk = 1; msk < 16; msk <<= 1) {
        pe4[j] += __shfl_xor(pe4[j], msk);
        sa4[j] += __shfl_xor(sa4[j], msk);
        top5_merge_x(t54[j], msk);
      }
    }

    if (l15 == 0) {
#pragma unroll
      for (int j = 0; j < 4; ++j) {
        float4* dp = (float4*)(part + ((size_t)(lr0 + j) * 2 + wn) * 8);
        dp[0] = make_float4(pe4[j], sa4[j], t54[j][0], t54[j][1]);
        dp[1] = make_float4(t54[j][2], t54[j][3], t54[j][4], 0.f);
      }
    }
  }

  __syncthreads();

  // ---- combine the 2 wn-partials per row, write STATS ----
  if (tid < BM) {
    const float* p0 = part + (size_t)tid * 2 * 8;
    float pe = 0.f, sa = 0.f;
    float t5[5] = {NEGINF, NEGINF, NEGINF, NEGINF, NEGINF};
#pragma unroll
    for (int q = 0; q < 2; ++q) {
      const float4 a = *(const float4*)(p0 + q * 8);
      const float4 b = *(const float4*)(p0 + q * 8 + 4);
      pe += a.x; sa += a.y;
      top5_insert(t5, a.z); top5_insert(t5, a.w);
      top5_insert(t5, b.x); top5_insert(t5, b.y); top5_insert(t5, b.z);
    }
    float4* dst = (float4*)(STATS + ((size_t)(rowbase + tid) * NCHUNK + ch) * 8);
    dst[0] = make_float4(pe, sa, t5[0], t5[1]);
    dst[1] = make_float4(t5[2], t5[3], t5[4], 0.f);
  }
}

// ---------------- kernel 3: per-row finalize -> per-block partial ----------------
__global__ __launch_bounds__(256) void k_rowloss(const float* __restrict__ STATS,
                                                 const long long* __restrict__ LAB,
                                                 const float* __restrict__ DDIAG,
                                                 const int* __restrict__ HIST,
                                                 float* __restrict__ PART) {
  const int row = blockIdx.x * 256 + threadIdx.x;
  const float* sp = STATS + (size_t)row * NCHUNK * 8;
  float pe = 0.f, sa = 0.f;
  float t5[5] = {NEGINF, NEGINF, NEGINF, NEGINF, NEGINF};
  for (int c = 0; c < NCHUNK; ++c) {
    const float4 q0 = *(const float4*)(sp + c * 8);
    const float4 q1 = *(const float4*)(sp + c * 8 + 4);
    pe += q0.x; sa += q0.y;
    top5_insert(t5, q0.z); top5_insert(t5, q0.w);
    top5_insert(t5, q1.x); top5_insert(t5, q1.y); top5_insert(t5, q1.z);
  }
  const float ediag = exp2f(fmaf(DDIAG[row], C1, -C1));  // exp(s_ii - M)
  const float ne = sa - pe - ediag;                      // sum over true negatives
  const int cn = BATCH - HIST[(int)LAB[row]];            // num_neg
  const float EM = exp2f(-C1);                           // exp(0 - M)
  const float sneg = ne + (float)(BATCH - cn) * EM;      // exp_neg_sum (zeros incl.)
  const int kf = cn < 5 ? cn : 5;
  float eh[5], Sh = 0.f;
#pragma unroll
  for (int k = 0; k < 5; ++k) {
    const float dk = (k < kf) ? t5[k] : 0.f;             // top-5 as dot values
    eh[k] = exp2f(fmaf(dk, C1, -C1));                    // exp(dk*INVT - M)
    Sh += eh[k];
  }
  float lsum = 0.f;
#pragma unroll
  for (int k = 0; k < 5; ++k) {
    const float denom = pe + Sh + sneg - eh[k];
    lsum += __logf(pe / (denom + EPSV) + EPSV);
  }
#pragma unroll
  for (int m = 32; m >= 1; m >>= 1) lsum += __shfl_xor(lsum, m);
  __shared__ float wsum[4];
  if ((threadIdx.x & 63) == 0) wsum[threadIdx.x >> 6] = lsum;
  __syncthreads();
  if (threadIdx.x == 0) PART[blockIdx.x] = wsum[0] + wsum[1] + wsum[2] + wsum[3];
}

// ---------------- kernel 4: final deterministic reduce ----------------
__global__ void k_final(const float* __restrict__ PART, float* __restrict__ OUT) {
  if (threadIdx.x == 0) {
    float s = 0.f;
    for (int i = 0; i < 16; ++i) s += PART[i];
    OUT[0] = -s / (float)(BATCH * 5);
  }
}

extern "C" void kernel_launch(void* const* d_in, const int* in_sizes, int n_in,
                              void* d_out, int out_size, void* d_ws, size_t ws_size,
                              hipStream_t stream) {
  const float* X = (const float*)d_in[0];
  const long long* LAB = (const long long*)d_in[1];
  float* OUT = (float*)d_out;

  unsigned short* F = (unsigned short*)d_ws;                                   // 8 MB bf16
  float* STATS = (float*)((char*)d_ws + (size_t)8 * 1024 * 1024);              // 2 MB
  float* PART  = (float*)((char*)d_ws + (size_t)12 * 1024 * 1024);             // 64 B
  float* DDIAG = (float*)((char*)d_ws + (size_t)12 * 1024 * 1024 + 4096);      // 16 KB
  int*   HIST  = (int*)((char*)d_ws + (size_t)12 * 1024 * 1024 + 4096 + 16384); // 2 KB

  k_hist<<<1, 1024, 0, stream>>>(LAB, HIST);
  k_normalize<<<BATCH / 4, 256, 0, stream>>>(X, F, DDIAG);
  dim3 g2(BATCH / BN, BATCH / BM);
  k_fused<<<g2, 256, 0, stream>>>(F, LAB, STATS);
  k_rowloss<<<BATCH / 256, 256, 0, stream>>>(STATS, LAB, DDIAG, HIST, PART);
  k_final<<<1, 64, 0, stream>>>(PART, OUT);
}

// Round 21
// 73.145 us; speedup vs baseline: 1.5191x; 1.0080x over previous
//
#include <hip/hip_runtime.h>
#include <hip/hip_bf16.h>

#define BATCH  4096
#define DIM    1024
#define NCHUNK 16          // 256-col chunks per row in STATS
#define BM     128
#define BN     256
#define BKK    64
#define NKT    (DIM / BKK) // 16 K-tiles
#define INVT   14.285714285714286f
#define C1     20.609929f  // INVT * log2(e); exp(INVT*(d-1)) == exp2(d*C1 - C1)
#define EPSV   1e-8f
#define NEGINF -3.0e38f

typedef __bf16 bf16x8 __attribute__((ext_vector_type(8)));
typedef float  f32x4  __attribute__((ext_vector_type(4)));
typedef __attribute__((address_space(3))) void lds_void;
typedef __attribute__((address_space(1))) void gl_void;

// Branchless sorted-desc top-5 insert (9 min/max ops).
__device__ __forceinline__ void top5_insert(float (&t)[5], float v) {
  float a = fmaxf(t[4], v), b;
  b = t[3]; t[4] = fminf(b, a); a = fmaxf(b, a);
  b = t[2]; t[3] = fminf(b, a); a = fmaxf(b, a);
  b = t[1]; t[2] = fminf(b, a); a = fmaxf(b, a);
  b = t[0]; t[1] = fminf(b, a); t[0] = fmaxf(b, a);
}

__device__ __forceinline__ void ce_desc(float& a, float& b) {
  const float hi = fmaxf(a, b), lo = fminf(a, b);
  a = hi; b = lo;
}

// Merge sorted-desc top5 with lane^msk's: elementwise max vs reversed partner
// list = top-5 multiset; 9-CE network re-sorts.
__device__ __forceinline__ void top5_merge_x(float (&t)[5], int msk) {
  const float b0 = __shfl_xor(t[0], msk);
  const float b1 = __shfl_xor(t[1], msk);
  const float b2 = __shfl_xor(t[2], msk);
  const float b3 = __shfl_xor(t[3], msk);
  const float b4 = __shfl_xor(t[4], msk);
  t[0] = fmaxf(t[0], b4); t[1] = fmaxf(t[1], b3); t[2] = fmaxf(t[2], b2);
  t[3] = fmaxf(t[3], b1); t[4] = fmaxf(t[4], b0);
  ce_desc(t[0], t[1]); ce_desc(t[3], t[4]); ce_desc(t[2], t[4]);
  ce_desc(t[2], t[3]); ce_desc(t[1], t[4]); ce_desc(t[0], t[3]);
  ce_desc(t[0], t[2]); ce_desc(t[1], t[3]); ce_desc(t[1], t[2]);
}

// ---------------- kernel 0: label histogram ----------------
__global__ __launch_bounds__(1024) void k_hist(const long long* __restrict__ LAB,
                                               int* __restrict__ HIST) {
  __shared__ int h[512];
  const int t = threadIdx.x;
  if (t < 512) h[t] = 0;
  __syncthreads();
  for (int i = t; i < BATCH; i += 1024) atomicAdd(&h[(int)LAB[i]], 1);
  __syncthreads();
  if (t < 512) HIST[t] = h[t];
}

// ---------------- kernel 1: row L2-normalize fp32 -> bf16 (+ bf16 self-dot) ----------------
// Wave-per-row: 4 rows/block, pure shfl reduction (no LDS, no __syncthreads).
__global__ __launch_bounds__(256) void k_normalize(const float* __restrict__ X,
                                                   unsigned short* __restrict__ F,
                                                   float* __restrict__ DDIAG) {
  const int row = blockIdx.x * 4 + (threadIdx.x >> 6);
  const int l   = threadIdx.x & 63;
  const float4* xp = (const float4*)(X + (size_t)row * DIM);
  float4 v[4];
  float ss = 0.f;
#pragma unroll
  for (int i = 0; i < 4; ++i) {
    v[i] = xp[l + 64 * i];
    ss += v[i].x*v[i].x + v[i].y*v[i].y + v[i].z*v[i].z + v[i].w*v[i].w;
  }
#pragma unroll
  for (int m = 32; m >= 1; m >>= 1) ss += __shfl_xor(ss, m);
  const float inv = 1.0f / fmaxf(sqrtf(ss), 1e-12f);
  ushort4* fp = (ushort4*)(F + (size_t)row * DIM);
  float s2 = 0.f;
#pragma unroll
  for (int i = 0; i < 4; ++i) {
    const __bf16 b0 = (__bf16)(v[i].x * inv), b1 = (__bf16)(v[i].y * inv);
    const __bf16 b2 = (__bf16)(v[i].z * inv), b3 = (__bf16)(v[i].w * inv);
    const float f0 = (float)b0, f1 = (float)b1, f2 = (float)b2, f3 = (float)b3;
    s2 += f0*f0 + f1*f1 + f2*f2 + f3*f3;   // self-dot of bf16-rounded row
    ushort4 o;
    o.x = __builtin_bit_cast(unsigned short, b0);
    o.y = __builtin_bit_cast(unsigned short, b1);
    o.z = __builtin_bit_cast(unsigned short, b2);
    o.w = __builtin_bit_cast(unsigned short, b3);
    fp[l + 64 * i] = o;
  }
#pragma unroll
  for (int m = 32; m >= 1; m >>= 1) s2 += __shfl_xor(s2, m);
  if (l == 0) DDIAG[row] = s2;
}

// ---------------- kernel 2: fused sim GEMM + per-row stats (128x256) ----------------
// grid = (16 ch, 32 rb), 256 thr = 4 waves (2M x 2N), wave tile 64x128 =
// acc[4][8]. Single-buffered 48 KB LDS, 2-barrier loop; 2 blocks/CU
// co-residency is the latency-hiding mechanism. Measured plateau of this
// structure: 54.5 us (640 TF effective, MfmaUtil ~25%); 10 structural
// variants (schedules, tiles, occupancy, operand paths, orderings) all
// null or negative. The path past it is an inline-asm K-loop (AITER-style
// counted-vmcnt across barriers), which the HIP compiler defeats at source
// level (guide m131-m141; reproduced in R8/R13).
__global__ __launch_bounds__(256, 2) void k_fused(const unsigned short* __restrict__ F,
                                                  const long long* __restrict__ LAB,
                                                  float* __restrict__ STATS) {
  __shared__ __align__(16) unsigned short lA[BM * BKK];  // 16 KB
  __shared__ __align__(16) unsigned short lB[BN * BKK];  // 32 KB

  const int ch  = blockIdx.x;
  const int rb  = blockIdx.y;
  const int tid = threadIdx.x;
  const int wid = tid >> 6;
  const int l   = tid & 63;
  const int l15 = l & 15;
  const int l4  = l >> 4;
  const int wm  = wid >> 1;        // 0..1
  const int wn  = wid & 1;         // 0..1
  const int swz = (l15 & 7) << 4;  // XOR swizzle: row%8 == l15&7 for frag reads
  const int rowbase = rb * BM;
  const int colbase = ch * BN;

  f32x4 acc[4][8];
#pragma unroll
  for (int mf = 0; mf < 4; ++mf)
#pragma unroll
    for (int nf = 0; nf < 8; ++nf) acc[mf][nf] = (f32x4){0.f, 0.f, 0.f, 0.f};

  // Precomputed staging addresses. Linear LDS dest, global source pre-swizzled
  // (16B chunk c fetched from chunk c^(r&7); involution within the 128B row).
  const unsigned short* gArow[4];
  const unsigned short* gBrow[8];
  int ldsoA[4], ldsoB[8];
#pragma unroll
  for (int it = 0; it < 4; ++it) {
    const int s = it * 256 + tid;
    const int r = s >> 3;
    const int c = (s & 7) ^ (r & 7);
    ldsoA[it] = s * 16;
    gArow[it] = F + (size_t)(rowbase + r) * DIM + c * 8;
  }
#pragma unroll
  for (int it = 0; it < 8; ++it) {
    const int s = it * 256 + tid;
    const int r = s >> 3;
    const int c = (s & 7) ^ (r & 7);
    ldsoB[it] = s * 16;
    gBrow[it] = F + (size_t)(colbase + r) * DIM + c * 8;
  }

  // ---- K loop: 2-barrier, single-buffered ----
#pragma unroll 1
  for (int kt = 0; kt < NKT; ++kt) {
    __syncthreads();                         // prev compute's LDS reads done
#pragma unroll
    for (int it = 0; it < 4; ++it)
      __builtin_amdgcn_global_load_lds((gl_void*)(gArow[it] + kt * BKK),
                                       (lds_void*)((char*)lA + ldsoA[it]), 16, 0, 0);
#pragma unroll
    for (int it = 0; it < 8; ++it)
      __builtin_amdgcn_global_load_lds((gl_void*)(gBrow[it] + kt * BKK),
                                       (lds_void*)((char*)lB + ldsoB[it]), 16, 0, 0);
    __syncthreads();                         // vmcnt(0) drain + barrier

#pragma unroll
    for (int kk = 0; kk < 2; ++kk) {
      bf16x8 av[4], bv[8];
      const int cx = (kk * 64 + l4 * 16) ^ swz;
#pragma unroll
      for (int mf = 0; mf < 4; ++mf)
        av[mf] = *(const bf16x8*)((const char*)lA + (wm * 64 + mf * 16 + l15) * 128 + cx);
#pragma unroll
      for (int nf = 0; nf < 8; ++nf)
        bv[nf] = *(const bf16x8*)((const char*)lB + (wn * 128 + nf * 16 + l15) * 128 + cx);
#pragma unroll
      for (int mf = 0; mf < 4; ++mf)
#pragma unroll
        for (int nf = 0; nf < 8; ++nf)
          acc[mf][nf] = __builtin_amdgcn_mfma_f32_16x16x32_bf16(av[mf], bv[nf], acc[mf][nf], 0, 0, 0);
    }
  }

  __syncthreads();   // all LDS reads done before part-overlay writes

  // ---- epilogue: per-row stats, mf FULLY UNROLLED (static acc indexing) ----
  float* part = (float*)lA;          // overlay: [128 rows][2 wn][8 floats] = 8 KB
  const bool hasdiag = ((rb >> 1) == ch);   // 128-row band intersects 256-col band

  int cl[8];
#pragma unroll
  for (int nf = 0; nf < 8; ++nf)
    cl[nf] = (int)LAB[colbase + wn * 128 + nf * 16 + l15];

#pragma unroll
  for (int mf = 0; mf < 4; ++mf) {
    const int lr0 = wm * 64 + mf * 16 + l4 * 4;   // local row of j=0
    int rlv[4];
#pragma unroll
    for (int j = 0; j < 4; ++j) rlv[j] = (int)LAB[rowbase + lr0 + j];

    float pe4[4], sa4[4], t54[4][5];
#pragma unroll
    for (int j = 0; j < 4; ++j) {
      pe4[j] = 0.f; sa4[j] = 0.f;
#pragma unroll
      for (int k = 0; k < 5; ++k) t54[j][k] = NEGINF;
    }

#define EPI_BODY(POSEXPR)                                      \
    _Pragma("unroll")                                          \
    for (int nf = 0; nf < 8; ++nf) {                           \
      _Pragma("unroll")                                        \
      for (int j = 0; j < 4; ++j) {                            \
        const float d = acc[mf][nf][j];                        \
        const float e = exp2f(fmaf(d, C1, -C1));               \
        const bool same = (rlv[j] == cl[nf]);                  \
        pe4[j] += (POSEXPR) ? e : 0.f;                         \
        sa4[j] += e;                                           \
        top5_insert(t54[j], same ? 0.f : d);                   \
      }                                                        \
    }

    if (hasdiag) {
      EPI_BODY(same && ((rowbase + lr0 + j) != (colbase + wn * 128 + nf * 16 + l15)))
    } else {
      EPI_BODY(same)
    }
#undef EPI_BODY

    // merge the 16 lanes (l15) holding each row
#pragma unroll
    for (int j = 0; j < 4; ++j) {
#pragma unroll
      for (int msk = 1; msk < 16; msk <<= 1) {
        pe4[j] += __shfl_xor(pe4[j], msk);
        sa4[j] += __shfl_xor(sa4[j], msk);
        top5_merge_x(t54[j], msk);
      }
    }

    if (l15 == 0) {
#pragma unroll
      for (int j = 0; j < 4; ++j) {
        float4* dp = (float4*)(part + ((size_t)(lr0 + j) * 2 + wn) * 8);
        dp[0] = make_float4(pe4[j], sa4[j], t54[j][0], t54[j][1]);
        dp[1] = make_float4(t54[j][2], t54[j][3], t54[j][4], 0.f);
      }
    }
  }

  __syncthreads();

  // ---- combine the 2 wn-partials per row, write STATS ----
  if (tid < BM) {
    const float* p0 = part + (size_t)tid * 2 * 8;
    float pe = 0.f, sa = 0.f;
    float t5[5] = {NEGINF, NEGINF, NEGINF, NEGINF, NEGINF};
#pragma unroll
    for (int q = 0; q < 2; ++q) {
      const float4 a = *(const float4*)(p0 + q * 8);
      const float4 b = *(const float4*)(p0 + q * 8 + 4);
      pe += a.x; sa += a.y;
      top5_insert(t5, a.z); top5_insert(t5, a.w);
      top5_insert(t5, b.x); top5_insert(t5, b.y); top5_insert(t5, b.z);
    }
    float4* dst = (float4*)(STATS + ((size_t)(rowbase + tid) * NCHUNK + ch) * 8);
    dst[0] = make_float4(pe, sa, t5[0], t5[1]);
    dst[1] = make_float4(t5[2], t5[3], t5[4], 0.f);
  }
}

// ---------------- kernel 3: per-row finalize -> per-block partial ----------------
__global__ __launch_bounds__(256) void k_rowloss(const float* __restrict__ STATS,
                                                 const long long* __restrict__ LAB,
                                                 const float* __restrict__ DDIAG,
                                                 const int* __restrict__ HIST,
                                                 float* __restrict__ PART) {
  const int row = blockIdx.x * 256 + threadIdx.x;
  const float* sp = STATS + (size_t)row * NCHUNK * 8;
  float pe = 0.f, sa = 0.f;
  float t5[5] = {NEGINF, NEGINF, NEGINF, NEGINF, NEGINF};
  for (int c = 0; c < NCHUNK; ++c) {
    const float4 q0 = *(const float4*)(sp + c * 8);
    const float4 q1 = *(const float4*)(sp + c * 8 + 4);
    pe += q0.x; sa += q0.y;
    top5_insert(t5, q0.z); top5_insert(t5, q0.w);
    top5_insert(t5, q1.x); top5_insert(t5, q1.y); top5_insert(t5, q1.z);
  }
  const float ediag = exp2f(fmaf(DDIAG[row], C1, -C1));  // exp(s_ii - M)
  const float ne = sa - pe - ediag;                      // sum over true negatives
  const int cn = BATCH - HIST[(int)LAB[row]];            // num_neg
  const float EM = exp2f(-C1);                           // exp(0 - M)
  const float sneg = ne + (float)(BATCH - cn) * EM;      // exp_neg_sum (zeros incl.)
  const int kf = cn < 5 ? cn : 5;
  float eh[5], Sh = 0.f;
#pragma unroll
  for (int k = 0; k < 5; ++k) {
    const float dk = (k < kf) ? t5[k] : 0.f;             // top-5 as dot values
    eh[k] = exp2f(fmaf(dk, C1, -C1));                    // exp(dk*INVT - M)
    Sh += eh[k];
  }
  float lsum = 0.f;
#pragma unroll
  for (int k = 0; k < 5; ++k) {
    const float denom = pe + Sh + sneg - eh[k];
    lsum += __logf(pe / (denom + EPSV) + EPSV);
  }
#pragma unroll
  for (int m = 32; m >= 1; m >>= 1) lsum += __shfl_xor(lsum, m);
  __shared__ float wsum[4];
  if ((threadIdx.x & 63) == 0) wsum[threadIdx.x >> 6] = lsum;
  __syncthreads();
  if (threadIdx.x == 0) PART[blockIdx.x] = wsum[0] + wsum[1] + wsum[2] + wsum[3];
}

// ---------------- kernel 4: final deterministic reduce ----------------
__global__ void k_final(const float* __restrict__ PART, float* __restrict__ OUT) {
  if (threadIdx.x == 0) {
    float s = 0.f;
    for (int i = 0; i < 16; ++i) s += PART[i];
    OUT[0] = -s / (float)(BATCH * 5);
  }
}

extern "C" void kernel_launch(void* const* d_in, const int* in_sizes, int n_in,
                              void* d_out, int out_size, void* d_ws, size_t ws_size,
                              hipStream_t stream) {
  const float* X = (const float*)d_in[0];
  const long long* LAB = (const long long*)d_in[1];
  float* OUT = (float*)d_out;

  unsigned short* F = (unsigned short*)d_ws;                                   // 8 MB bf16
  float* STATS = (float*)((char*)d_ws + (size_t)8 * 1024 * 1024);              // 2 MB
  float* PART  = (float*)((char*)d_ws + (size_t)12 * 1024 * 1024);             // 64 B
  float* DDIAG = (float*)((char*)d_ws + (size_t)12 * 1024 * 1024 + 4096);      // 16 KB
  int*   HIST  = (int*)((char*)d_ws + (size_t)12 * 1024 * 1024 + 4096 + 16384); // 2 KB

  k_hist<<<1, 1024, 0, stream>>>(LAB, HIST);
  k_normalize<<<BATCH / 4, 256, 0, stream>>>(X, F, DDIAG);
  dim3 g2(BATCH / BN, BATCH / BM);
  k_fused<<<g2, 256, 0, stream>>>(F, LAB, STATS);
  k_rowloss<<<BATCH / 256, 256, 0, stream>>>(STATS, LAB, DDIAG, HIST, PART);
  k_final<<<1, 64, 0, stream>>>(PART, OUT);
}